// Round 9
// baseline (927.732 us; speedup 1.0000x reference)
//
#include <hip/hip_runtime.h>

namespace {
constexpr int NB = 1024, NT = 1024, NH = 128;
constexpr float L2E = 1.4426950408889634f;

typedef __bf16 bf16x8 __attribute__((ext_vector_type(8)));
typedef float  f32x4  __attribute__((ext_vector_type(4)));
typedef int    i32x4  __attribute__((ext_vector_type(4)));
union FRAG { i32x4 i; bf16x8 b; };

__device__ __forceinline__ unsigned short bfb(float f) {   // HW RNE f32->bf16
  union { __bf16 h; unsigned short u; } c; c.h = (__bf16)f; return c.u;
}
__device__ __forceinline__ unsigned pkbf(float a, float b) {
  return (unsigned)bfb(a) | ((unsigned)bfb(b) << 16);
}
__device__ __forceinline__ unsigned long long pk4(const f32x4 v) {
  return (unsigned long long)pkbf(v[0], v[1]) |
         ((unsigned long long)pkbf(v[2], v[3]) << 32);
}
__device__ __forceinline__ float ex2(float x) { return __builtin_amdgcn_exp2f(x); }
__device__ __forceinline__ float rcp_(float x) { return __builtin_amdgcn_rcpf(x); }

// 8 consecutive floats -> bf16 fragment (k = 32s + 8lg + j map, verified r0/r1)
__device__ __forceinline__ FRAG pk8(const float* pp, float sc) {
  FRAG f;
  #pragma unroll
  for (int j = 0; j < 4; ++j)
    f.i[j] = (int)pkbf(pp[2 * j] * sc, pp[2 * j + 1] * sc);
  return f;
}
} // namespace

#define MFMA(a, b, c) __builtin_amdgcn_mfma_f32_16x16x32_bf16(a, b, c, 0, 0, 0)
// LDS-only barrier: never drains vmcnt (global h-stream / x-prefetch in flight)
#define BAR() do { \
  asm volatile("s_waitcnt lgkmcnt(0)" ::: "memory"); \
  __builtin_amdgcn_s_barrier(); \
} while (0)

// ---------------------------------------------------------------------------
// Combined kernel, grid = 256 x 512 threads.
//   blocks 0-63  : rnn role — 4 GATE waves (wave wv<4 owns units [32wv,32wv+32)
//                  as two 16-unit tiles; 30 MFMA/wave) -> LDS B-fragment read
//                  volume halved vs 8-wave (the round-7 bottleneck model).
//                  Waves 4-5: x_hat lanes. Waves 6-7: x stagers. One LDS-only
//                  barrier per step. h_t streamed to hcur (4KB [b][u] tiles).
//   blocks 64-255: head role — VERBATIM round 7 (verified): processes chunk
//                  [t0p,t0p+Tc) from hprev (previous dispatch), overlapped.
// ---------------------------------------------------------------------------
__global__ __launch_bounds__(512, 2)
void grud_combo(const float* __restrict__ x, const float* __restrict__ x_mean,
                const float* __restrict__ dxw, const float* __restrict__ dxb,
                const float* __restrict__ dhw, const float* __restrict__ dhb,
                const float* __restrict__ w_ih, const float* __restrict__ w_hh,
                const float* __restrict__ b_ih, const float* __restrict__ b_hh,
                const float* __restrict__ w1, const float* __restrict__ b1,
                const float* __restrict__ w2, const float* __restrict__ b2,
                const float* __restrict__ wu1, const float* __restrict__ bu1,
                const float* __restrict__ wu2, const float* __restrict__ bu2,
                float* __restrict__ out,
                char* __restrict__ hcur, const char* __restrict__ hprev,
                float* __restrict__ hstate, float* __restrict__ runst,
                float* __restrict__ xlst, int t0, int t0p, int Tc, int niter)
{
  __shared__ __align__(16) char lds[40960];

  const int tid = threadIdx.x;
  const int lane = tid & 63, wv = tid >> 6;
  const int lr = lane & 15, lg = lane >> 4;

  if (blockIdx.x < 64) {
    // ============================ RNN ROLE ============================
    if (t0 >= NT) return;

    float (*xw)[16][17] = (float(*)[16][17])lds;                    // 2176 B
    unsigned short (*gin)[16][40] = (unsigned short(*)[16][40])(lds + 2176); // 2560 B
    char* hdL = lds + 4736;                                         // 8192 B

    const int b0 = blockIdx.x * 16;
    const bool gw = (wv < 4);
    const int uB = (wv & 3) * 32;      // gate wave's unit base

    // ---- gate-wave weight fragments (r,z scaled -log2e; n +2log2e) ----
    FRAG whh[3][2][4], wgi[3][2];
    f32x4 dhwV[2], dhbV[2], bhnV[2];
    if (gw) {
      #pragma unroll
      for (int g = 0; g < 3; ++g) {
        const float sc = (g < 2) ? -L2E : 2.f * L2E;
        #pragma unroll
        for (int tau = 0; tau < 2; ++tau) {
          const int grow = g * 128 + uB + 16 * tau + lr;
          const float* wrow = w_hh + (size_t)grow * NH;
          #pragma unroll
          for (int s = 0; s < 4; ++s)
            whh[g][tau][s] = pk8(wrow + 32 * s + 8 * lg, sc);
          FRAG f; f.i = i32x4{0, 0, 0, 0};
          if (lg < 2) {
            unsigned e[8];
            #pragma unroll
            for (int j = 0; j < 8; ++j) {
              const int c = 8 * lg + j; float v = 0.f;
              if (c < 12) {
                const int ch = c >> 1;
                v = ((c & 1) ? w_ih[(size_t)grow * 12 + 6 + ch]
                             : w_ih[(size_t)grow * 12 + ch]) * sc;
              } else if (c == 12) {
                v = ((g < 2) ? (b_ih[grow] + b_hh[grow]) : b_ih[grow]) * sc;
              }
              e[j] = bfb(v);
            }
            f.i[0] = (int)(e[0] | (e[1] << 16)); f.i[1] = (int)(e[2] | (e[3] << 16));
            f.i[2] = (int)(e[4] | (e[5] << 16)); f.i[3] = (int)(e[6] | (e[7] << 16));
          }
          wgi[g][tau] = f;
        }
      }
      #pragma unroll
      for (int tau = 0; tau < 2; ++tau) {
        const int u0 = uB + 16 * tau + 4 * lg;
        #pragma unroll
        for (int r = 0; r < 4; ++r) {
          dhwV[tau][r] = -L2E * dhw[u0 + r];
          dhbV[tau][r] = -L2E * dhb[u0 + r];
          bhnV[tau][r] = b_hh[256 + u0 + r] * (2.f * L2E);
        }
      }
    }

    // ---- x̂ lanes: waves 4-5 (96 items) ----
    const int xi = (wv - 4) * 64 + lane;
    const bool xl = (wv == 4) || (wv == 5 && lane < 32);
    const int xrow = xi / 6, xch = xi - 6 * (xi / 6);
    float dxwS = 0.f, dxbS = 0.f, xm_l = 0.f, run = 0.f, xlast = 0.f;
    if (xl) {
      dxwS = -L2E * dxw[xch]; dxbS = -L2E * dxb[xch]; xm_l = x_mean[xch];
      if (t0 > 0) { run = runst[(b0 + xrow) * 6 + xch]; xlast = xlst[(b0 + xrow) * 6 + xch]; }
    }

    // ---- stagers: waves 6-7, items sid and sid+128 (208 total) ----
    const int sid = (wv - 6) * 64 + lane;
    const bool s1 = (wv >= 6);
    const bool s2 = s1 && (sid < 80);
    const int r1r = sid / 13, r1c = sid - 13 * r1r;
    const int r2r = (sid + 128) / 13, r2c = (sid + 128) - 13 * r2r;
    const float* xb1 = x + (size_t)(b0 + r1r) * (NT * 13) + r1c;
    const float* xb2 = x + (size_t)(b0 + r2r) * (NT * 13) + r2c;

    // ---- h state: lane holds (batch lr, units uB+16tau+4lg..+3) ----
    f32x4 hn0 = {0.f,0.f,0.f,0.f}, hn1 = {0.f,0.f,0.f,0.f};
    if (gw && t0 > 0) {
      hn0 = *(const f32x4*)&hstate[(size_t)(b0 + lr) * NH + uB + 4 * lg];
      hn1 = *(const f32x4*)&hstate[(size_t)(b0 + lr) * NH + uB + 16 + 4 * lg];
    }

    // ---- constant LDS byte offsets ----
    int wOffT[2], rOff[4];
    #pragma unroll
    for (int tau = 0; tau < 2; ++tau) {
      const int cell = ((uB + 16 * tau + 4 * lg) >> 3);
      wOffT[tau] = lr * 256 + ((cell ^ (lr & 7)) << 4) + (lg & 1) * 8;
    }
    #pragma unroll
    for (int s = 0; s < 4; ++s) rOff[s] = lr * 256 + (((4 * s + lg) ^ (lr & 7)) << 4);

    // ---- gin tails (cols 12..39: bias col 12 = 1.0; both buffers) ----
    for (int i = tid; i < 2 * 16 * 28; i += 512) {
      const int buf = i / 448, rem = i - 448 * buf;
      const int row = rem / 28, c = 12 + rem - 28 * (rem / 28);
      gin[buf][row][c] = (c == 12) ? (unsigned short)0x3F80 : (unsigned short)0;
    }

    // ---- prologue ----
    const int cb0 = t0 & 1;
    if (s1) {
      const int t1 = (t0 + 1 < NT) ? t0 + 1 : NT - 1;
      xw[cb0][r1r][r1c]     = xb1[(size_t)t0 * 13];
      xw[cb0 ^ 1][r1r][r1c] = xb1[(size_t)t1 * 13];
      if (s2) {
        xw[cb0][r2r][r2c]     = xb2[(size_t)t0 * 13];
        xw[cb0 ^ 1][r2r][r2c] = xb2[(size_t)t1 * 13];
      }
    }
    __syncthreads();

    f32x4 hd0, hd1;
    if (gw) {
      const float dt0 = xw[cb0][lr][12];
      #pragma unroll
      for (int r = 0; r < 4; ++r) {
        hd0[r] = ex2(fminf(dt0 * dhwV[0][r] + dhbV[0][r], 0.f)) * hn0[r];
        hd1[r] = ex2(fminf(dt0 * dhwV[1][r] + dhbV[1][r], 0.f)) * hn1[r];
      }
      *(unsigned long long*)(hdL + cb0 * 4096 + wOffT[0]) = pk4(hd0);
      *(unsigned long long*)(hdL + cb0 * 4096 + wOffT[1]) = pk4(hd1);
    }
    if (xl) {
      const float xv = xw[cb0][xrow][xch], mt = xw[cb0][xrow][6 + xch];
      const float dtv = xw[cb0][xrow][12];
      const bool obs = mt > 0.5f;
      run = obs ? 0.f : run + dtv;
      const float gx = ex2(fminf(run * dxwS + dxbS, 0.f));
      xlast = obs ? xv : xlast;
      const float xh = mt * xv + (1.f - mt) * (gx * xlast + (1.f - gx) * xm_l);
      ((unsigned*)&gin[cb0][xrow][0])[xch] = pkbf(xh, mt);
    }
    float xr2a = 0.f, xr2b = 0.f;
    if (s1) {
      const int t2 = (t0 + 2 < NT) ? t0 + 2 : NT - 1;
      xr2a = xb1[(size_t)t2 * 13];
      if (s2) xr2b = xb2[(size_t)t2 * 13];
    }
    BAR();

    char* hwp = hcur + (((size_t)blockIdx.x * Tc) << 12) + lr * 256 + (uB + 4 * lg) * 2;
    const f32x4 z4 = {0.f, 0.f, 0.f, 0.f};
    const int tend = t0 + Tc;

    #pragma unroll 1
    for (int t = t0; t < tend; ++t) {
      const int p = t & 1, q = p ^ 1;

      if (gw) {
        // gamma for t+1 hoisted (dt_{t+1} already staged)
        const float dtn = xw[q][lr][12];
        f32x4 gm0, gm1;
        #pragma unroll
        for (int r = 0; r < 4; ++r) {
          gm0[r] = ex2(fminf(dtn * dhwV[0][r] + dhbV[0][r], 0.f));
          gm1[r] = ex2(fminf(dtn * dhwV[1][r] + dhbV[1][r], 0.f));
        }

        FRAG ag; ag.i = *(const i32x4*)&gin[p][lr][8 * lg];
        FRAG ah[4];
        #pragma unroll
        for (int s = 0; s < 4; ++s)
          ah[s].i = *(const i32x4*)(hdL + p * 4096 + rOff[s]);

        f32x4 r0 = MFMA(wgi[0][0].b, ag.b, z4);
        f32x4 zz0 = MFMA(wgi[1][0].b, ag.b, z4);
        f32x4 ni0 = MFMA(wgi[2][0].b, ag.b, z4);
        f32x4 nh0 = z4;
        f32x4 r1 = MFMA(wgi[0][1].b, ag.b, z4);
        f32x4 zz1 = MFMA(wgi[1][1].b, ag.b, z4);
        f32x4 ni1 = MFMA(wgi[2][1].b, ag.b, z4);
        f32x4 nh1 = z4;
        #pragma unroll
        for (int s = 0; s < 4; ++s) {
          r0  = MFMA(whh[0][0][s].b, ah[s].b, r0);
          zz0 = MFMA(whh[1][0][s].b, ah[s].b, zz0);
          nh0 = MFMA(whh[2][0][s].b, ah[s].b, nh0);
          r1  = MFMA(whh[0][1][s].b, ah[s].b, r1);
          zz1 = MFMA(whh[1][1][s].b, ah[s].b, zz1);
          nh1 = MFMA(whh[2][1][s].b, ah[s].b, nh1);
        }

        // 5-trans tail per tile: hn = [(En-1)Ez + hd(En+1)] / [(En+1)(1+Ez)]
        f32x4 hb0 = nh0 + bhnV[0], hb1 = nh1 + bhnV[1];
        #pragma unroll
        for (int r = 0; r < 4; ++r) {
          {
            const float Er = ex2(r0[r]);
            const float rr = rcp_(1.f + Er);
            const float na = __builtin_fmaf(rr, hb0[r], ni0[r]);
            const float En = ex2(na);
            const float Ez = ex2(zz0[r]);
            const float em1 = En - 1.f, ep1 = En + 1.f;
            const float num = __builtin_fmaf(hd0[r], ep1, em1 * Ez);
            hn0[r] = num * rcp_(ep1 * (1.f + Ez));
          }
          {
            const float Er = ex2(r1[r]);
            const float rr = rcp_(1.f + Er);
            const float na = __builtin_fmaf(rr, hb1[r], ni1[r]);
            const float En = ex2(na);
            const float Ez = ex2(zz1[r]);
            const float em1 = En - 1.f, ep1 = En + 1.f;
            const float num = __builtin_fmaf(hd1[r], ep1, em1 * Ez);
            hn1[r] = num * rcp_(ep1 * (1.f + Ez));
          }
        }

        // stream h_t (2x8B/lane, never drained at barrier)
        *(unsigned long long*)hwp = pk4(hn0);
        *(unsigned long long*)(hwp + 32) = pk4(hn1);

        // decay for t+1 + LDS writes
        #pragma unroll
        for (int r = 0; r < 4; ++r) { hd0[r] = gm0[r] * hn0[r]; hd1[r] = gm1[r] * hn1[r]; }
        *(unsigned long long*)(hdL + q * 4096 + wOffT[0]) = pk4(hd0);
        *(unsigned long long*)(hdL + q * 4096 + wOffT[1]) = pk4(hd1);
      } else {
        if (xl && t + 1 < tend) {          // x̂ for t+1 (reads xw[q] -> gin[q])
          const float xv = xw[q][xrow][xch], mt = xw[q][xrow][6 + xch];
          const float dtv = xw[q][xrow][12];
          const bool obs = mt > 0.5f;
          run = obs ? 0.f : run + dtv;
          const float gx = ex2(fminf(run * dxwS + dxbS, 0.f));
          xlast = obs ? xv : xlast;
          const float xh = mt * xv + (1.f - mt) * (gx * xlast + (1.f - gx) * xm_l);
          ((unsigned*)&gin[q][xrow][0])[xch] = pkbf(xh, mt);
        }
        if (s1) {                          // stage x[t+2] -> xw[p]; prefetch
          const int t3 = (t + 3 < NT) ? t + 3 : NT - 1;
          xw[p][r1r][r1c] = xr2a;
          xr2a = xb1[(size_t)t3 * 13];
          if (s2) { xw[p][r2r][r2c] = xr2b; xr2b = xb2[(size_t)t3 * 13]; }
        }
      }
      hwp += 4096;
      BAR();
    }

    // ---- carry state ----
    if (gw) {
      *(f32x4*)&hstate[(size_t)(b0 + lr) * NH + uB + 4 * lg] = hn0;
      *(f32x4*)&hstate[(size_t)(b0 + lr) * NH + uB + 16 + 4 * lg] = hn1;
    }
    if (xl) { runst[(b0 + xrow) * 6 + xch] = run; xlst[(b0 + xrow) * 6 + xch] = xlast; }

  } else {
    // ==================== HEAD ROLE (round-7 verbatim) ====================
    if (t0p < 0) return;

    const int hb = blockIdx.x - 64;              // 0..191
    const int tid2 = tid & 255, half = tid >> 8; // two 4-wave halves
    const int lane2 = tid2 & 63, w4 = tid2 >> 6;
    const int lr2 = lane2 & 15, lg2 = lane2 >> 4;
    char* ldsH = lds + half * 20480;             // hs@0(8K), y1@8192(8K), u1@16384(4K)

    FRAG bw1a[4], bw1b[4], bq1[4], bw2[4], bq2[2];
    #pragma unroll
    for (int s = 0; s < 4; ++s) {
      bw1a[s] = pk8(w1 + (size_t)((2 * w4) * 16 + lr2) * 128 + 32 * s + 8 * lg2, 1.f);
      bw1b[s] = pk8(w1 + (size_t)((2 * w4 + 1) * 16 + lr2) * 128 + 32 * s + 8 * lg2, 1.f);
      bq1[s]  = pk8(wu1 + (size_t)(w4 * 16 + lr2) * 128 + 32 * s + 8 * lg2, 1.f);
      if (lr2 < 6) bw2[s] = pk8(w2 + (size_t)lr2 * 128 + 32 * s + 8 * lg2, 1.f);
      else         bw2[s].i = i32x4{0, 0, 0, 0};
      if (s < 2) {
        if (lr2 < 6) bq2[s] = pk8(wu2 + (size_t)lr2 * 64 + 32 * s + 8 * lg2, 1.f);
        else         bq2[s].i = i32x4{0, 0, 0, 0};
      }
    }
    const float b1a = b1[(2 * w4) * 16 + lr2], b1b = b1[(2 * w4 + 1) * 16 + lr2];
    const float bu1l = bu1[w4 * 16 + lr2];
    const float b2l = (lr2 < 6) ? b2[lr2] : 0.f, bu2l = (lr2 < 6) ? bu2[lr2] : 0.f;
    const f32x4 z4 = {0.f, 0.f, 0.f, 0.f};

    const int tc2 = Tc >> 1, total = 64 * tc2;
    const int cy0 = (2 * w4) * 16 + lr2, cy1 = (2 * w4 + 1) * 16 + lr2;
    const int cu = w4 * 16 + lr2;

    #pragma unroll 1
    for (int it = 0; it < niter; ++it) {
      const int hu = it * 384 + hb * 2 + half;
      const bool valid = hu < total;
      int chain = 0, tp = 0;
      if (valid) { chain = hu / tc2; tp = hu - chain * tc2; }

      if (valid) {   // stage 2 h tiles, cell-swizzled
        const char* src = hprev + (((size_t)chain * Tc + tp * 2) << 12);
        const int o = tid2 * 16, row = o >> 8, cell = (o >> 4) & 15;
        #pragma unroll
        for (int k2 = 0; k2 < 2; ++k2) {
          uint4 v = *(const uint4*)(src + k2 * 4096 + o);
          *(uint4*)(ldsH + k2 * 4096 + row * 256 + ((cell ^ (row & 7)) << 4)) = v;
        }
      }
      __syncthreads();

      if (valid) {   // layer 1 over 2 t-tiles
        #pragma unroll
        for (int k = 0; k < 2; ++k) {
          FRAG A[4];
          #pragma unroll
          for (int s = 0; s < 4; ++s)
            A[s].i = *(const i32x4*)(ldsH + k * 4096 + lr2 * 256 +
                                     (((4 * s + lg2) ^ (lr2 & 7)) << 4));
          f32x4 aa = z4, ab = z4, au = z4;
          #pragma unroll
          for (int s = 0; s < 4; ++s) {
            aa = MFMA(A[s].b, bw1a[s].b, aa);
            ab = MFMA(A[s].b, bw1b[s].b, ab);
            au = MFMA(A[s].b, bq1[s].b, au);
          }
          #pragma unroll
          for (int r = 0; r < 4; ++r) {
            const int m = k * 16 + 4 * lg2 + r;
            *(unsigned short*)(ldsH + 8192 + m * 256 + (((cy0 >> 3) ^ (m & 7)) << 4) +
                               (cy0 & 7) * 2) = bfb(fmaxf(aa[r] + b1a, 0.f));
            *(unsigned short*)(ldsH + 8192 + m * 256 + (((cy1 >> 3) ^ (m & 7)) << 4) +
                               (cy1 & 7) * 2) = bfb(fmaxf(ab[r] + b1b, 0.f));
            *(unsigned short*)(ldsH + 16384 + m * 128 + (((cu >> 3) ^ (m & 7)) << 4) +
                               (cu & 7) * 2) = bfb(fmaxf(au[r] + bu1l, 0.f));
          }
        }
      }
      __syncthreads();

      if (valid && w4 < 2) {   // layer 2: wave w4 finishes t-tile w4
        const int mrow = w4 * 16 + lr2;
        FRAG Y[4], U[2];
        #pragma unroll
        for (int s = 0; s < 4; ++s)
          Y[s].i = *(const i32x4*)(ldsH + 8192 + mrow * 256 +
                                   (((4 * s + lg2) ^ (lr2 & 7)) << 4));
        #pragma unroll
        for (int s = 0; s < 2; ++s)
          U[s].i = *(const i32x4*)(ldsH + 16384 + mrow * 128 +
                                   (((4 * s + lg2) ^ (lr2 & 7)) << 4));
        f32x4 ap = z4, aq = z4;
        #pragma unroll
        for (int s = 0; s < 4; ++s) ap = MFMA(Y[s].b, bw2[s].b, ap);
        #pragma unroll
        for (int s = 0; s < 2; ++s) aq = MFMA(U[s].b, bq2[s].b, aq);

        if (lr2 < 6) {
          const int t = t0p + tp * 2 + w4;
          #pragma unroll
          for (int r = 0; r < 4; ++r) {
            const int b = chain * 16 + 4 * lg2 + r;
            const size_t o = ((size_t)b * NT + t) * 6 + lr2;
            out[o] = ap[r] + b2l;
            const float xa = aq[r] + bu2l;
            const float sp = fmaxf(xa, 0.f) + 0.6931471805599453f *
                __builtin_amdgcn_logf(1.f + ex2(-fabsf(xa) * L2E));
            out[(size_t)NB * NT * 6 + o] = sp;
          }
        }
      }
      __syncthreads();
    }
  }
}

extern "C" void kernel_launch(void* const* d_in, const int* in_sizes, int n_in,
                              void* d_out, int out_size, void* d_ws, size_t ws_size,
                              hipStream_t stream) {
  (void)in_sizes; (void)n_in; (void)out_size;
  const float* p[18];
  for (int i = 0; i < 18; ++i) p[i] = (const float*)d_in[i];

  const size_t STATE = (size_t)1024 * 128 * 4 + 2 * (size_t)1024 * 6 * 4;
  int Tc = 256;   // small head-tail dispatch; hws dbuf fits ws
  while (Tc > 16 && (2 * ((size_t)Tc << 18) + STATE) > ws_size) Tc >>= 1;

  char* h0 = (char*)d_ws;
  char* h1 = h0 + ((size_t)Tc << 18);
  float* hstate = (float*)(h1 + ((size_t)Tc << 18));
  float* runst = hstate + 1024 * 128;
  float* xlst = runst + 1024 * 6;

  const int nch = NT / Tc;
  const int niter = (64 * (Tc / 2) + 383) / 384;

  for (int k = 0; k <= nch; ++k) {
    char* hcur = (k & 1) ? h1 : h0;
    const char* hprev = (k & 1) ? h0 : h1;
    hipLaunchKernelGGL(grud_combo, dim3(256), dim3(512), 0, stream,
                       p[0], p[1], p[2], p[3], p[4], p[5], p[6], p[7], p[8], p[9],
                       p[10], p[11], p[12], p[13], p[14], p[15], p[16], p[17],
                       (float*)d_out, hcur, hprev, hstate, runst, xlst,
                       k * Tc, (k - 1) * Tc, Tc, niter);
  }
}